// Round 9
// baseline (41.971 us; speedup 1.0000x reference)
//
#include <hip/hip_runtime.h>

#define TPB 512
#define NW  (TPB / 64)   // 8 waves per block

__device__ __forceinline__ float pair_loss(float p0, float s0, float p1, float s1) {
    float dp = p0 - p1;
    float ds = s0 - s1;
    float sg = (ds > 0.0f) ? 1.0f : ((ds < 0.0f) ? -1.0f : 0.0f);
    float t  = dp * sg;
    // stable softplus(-t) = max(-t,0) + log1p(exp(-|t|))
    return fmaxf(-t, 0.0f) + log1pf(__expf(-fabsf(t)));
}

// classic per-row stats (used only in the rare boundary scan)
__device__ __forceinline__ void row_stats(const float* __restrict__ outp, int row,
                                          float& p, bool& mask) {
    const float4* o4 = (const float4*)outp + (size_t)row * 4;
    float4 a = o4[0];
    float4 b = o4[1];
    float4 c = o4[2];
    float4 d = o4[3];
    float m01 = fmaxf(fmaxf(a.x, a.y), fmaxf(a.z, a.w));
    float m23 = fmaxf(fmaxf(b.x, b.y), fmaxf(b.z, b.w));
    float m45 = fmaxf(fmaxf(c.x, c.y), fmaxf(c.z, c.w));
    float m67 = fmaxf(fmaxf(d.x, d.y), fmaxf(d.z, d.w));
    float m = fmaxf(fmaxf(m01, m23), fmaxf(m45, m67));
    float sum = __expf(a.x - m) + __expf(a.y - m) + __expf(a.z - m) + __expf(a.w - m)
              + __expf(b.x - m) + __expf(b.y - m) + __expf(b.z - m) + __expf(b.w - m)
              + __expf(c.x - m) + __expf(c.y - m) + __expf(c.z - m) + __expf(c.w - m)
              + __expf(d.x - m) + __expf(d.y - m) + __expf(d.z - m) + __expf(d.w - m);
    p = __builtin_amdgcn_rcpf(sum);
    mask = (a.x == m);
}

// gather bits at nibble stride (0,4,8,12) of a 16-bit value into 4 dense bits
__device__ __forceinline__ unsigned int nib4(unsigned int x) {
    return (((x & 0x1111u) * 0x1248u) >> 12) & 0xFu;
}

// k1: coalesced loads (contiguous 1KB per wave VMEM instr) + 4-lane-group
//     softmax; pair phase identical to the 31.4us R6 structure.
__global__ void __launch_bounds__(TPB) k_fused(const float* __restrict__ outp,
                                               const float* __restrict__ score,
                                               float* __restrict__ bpart, int B) {
    __shared__ float sp[TPB];
    __shared__ float ss[TPB];
    __shared__ unsigned long long wmask[NW];
    __shared__ float wsum[NW];

    int tid  = threadIdx.x;
    int lane = tid & 63;
    int wid  = tid >> 6;
    int wrow0 = blockIdx.x * TPB + (wid << 6);   // wave's first row

    // ---- coalesced global loads: 4 x dwordx4, lane-contiguous ----
    const float4* b4 = (const float4*)outp;
    size_t f0   = (size_t)wrow0 * 4;             // first float4 index of wave span
    size_t fend = (size_t)B * 4;
    float4 z = make_float4(0.f, 0.f, 0.f, 0.f);
    float4 v0 = (f0 +   0 + lane < fend) ? b4[f0 +   0 + lane] : z;
    float4 v1 = (f0 +  64 + lane < fend) ? b4[f0 +  64 + lane] : z;
    float4 v2 = (f0 + 128 + lane < fend) ? b4[f0 + 128 + lane] : z;
    float4 v3 = (f0 + 192 + lane < fend) ? b4[f0 + 192 + lane] : z;
    float s = (wrow0 + lane < B) ? score[wrow0 + lane] : 0.0f;
    ss[(wid << 6) + lane] = s;                   // coalesced LDS write by row

    // ---- 4-lane-group softmax: lanes 4r..4r+3 own row j*16+r of this wave ----
    unsigned long long mym = 0;
#pragma unroll
    for (int j = 0; j < 4; ++j) {
        float4 x = (j == 0) ? v0 : (j == 1) ? v1 : (j == 2) ? v2 : v3;
        float m = fmaxf(fmaxf(x.x, x.y), fmaxf(x.z, x.w));
        m = fmaxf(m, __shfl_xor(m, 1));
        m = fmaxf(m, __shfl_xor(m, 2));          // row max on all 4 group lanes
        float e = __expf(x.x - m) + __expf(x.y - m) + __expf(x.z - m) + __expf(x.w - m);
        e += __shfl_xor(e, 1);
        e += __shfl_xor(e, 2);                   // row expsum on all 4 group lanes
        float x0 = __shfl(x.x, lane & ~3);       // class-0 logit (quarter-0 lane)
        int rowlocal = (wid << 6) + (j << 4) + (lane >> 2);
        bool msk = (x0 == m) && (blockIdx.x * TPB + rowlocal < B);
        if ((lane & 3) == 0) sp[rowlocal] = __builtin_amdgcn_rcpf(e);
        unsigned long long bal = __ballot(msk);  // 4-bit replicated groups
        unsigned int lo = (unsigned int)bal, hi = (unsigned int)(bal >> 32);
        unsigned int c = nib4(lo) | (nib4(lo >> 16) << 4)
                       | (nib4(hi) << 8) | (nib4(hi >> 16) << 12);
        mym |= (unsigned long long)c << (j << 4);
    }
    if (lane == 0) wmask[wid] = mym;
    __syncthreads();

    // ---- pair phase (identical to R6): thread tid owns row tid ----
    unsigned long long bal = wmask[wid];
    bool mask = (bal >> lane) & 1ull;
    float p   = sp[tid];
    float sc  = ss[tid];

    float acc = 0.0f;
    if (mask) {
        unsigned long long above = bal & ~((2ull << lane) - 1ull); // lane63 -> 0
        int nxt = -1;
        if (above) {
            nxt = (wid << 6) + __ffsll(above) - 1;
        } else {
            for (int w = wid + 1; w < NW; ++w)
                if (wmask[w]) { nxt = (w << 6) + __ffsll(wmask[w]) - 1; break; }
        }
        if (nxt >= 0) acc = pair_loss(p, sc, sp[nxt], ss[nxt]);
    }

    // wave 0: cross-block pair via forward scan into following rows
    if (wid == 0) {
        int last = -1;
        for (int w = NW - 1; w >= 0; --w)
            if (wmask[w]) { last = (w << 6) + 63 - __clzll(wmask[w]); break; }
        if (last >= 0) {
            float pl = sp[last];
            float sl = ss[last];
            int base = blockIdx.x * TPB + TPB;
            while (base < B) {
                int r = base + lane;
                bool sel = false;
                float pf = 0.0f, sf = 0.0f;
                if (r < B) {
                    row_stats(outp, r, pf, sel);
                    sf = score[r];
                }
                unsigned long long b2 = __ballot(sel);
                if (b2) {
                    int fl = __ffsll(b2) - 1;
                    float pfirst = __shfl(pf, fl);
                    float sfirst = __shfl(sf, fl);
                    if (lane == 0) acc += pair_loss(pl, sl, pfirst, sfirst);
                    break;
                }
                base += 64;
            }
        }
    }

    // block reduce -> contention-free partial write
    for (int off = 32; off > 0; off >>= 1) acc += __shfl_down(acc, off);
    if (lane == 0) wsum[wid] = acc;
    __syncthreads();
    if (tid == 0) {
        float t = 0.0f;
        for (int w = 0; w < NW; ++w) t += wsum[w];
        bpart[blockIdx.x] = t;
    }
}

// k2: single block sums the per-block partials, writes out[0].
__global__ void k2_sum(const float* __restrict__ bpart, int nb,
                       float* __restrict__ out) {
    __shared__ float wsum[16];
    float acc = 0.0f;
    for (int b = threadIdx.x; b < nb; b += 1024) acc += bpart[b];
    int lane = threadIdx.x & 63;
    int wid  = threadIdx.x >> 6;
    for (int off = 32; off > 0; off >>= 1) acc += __shfl_down(acc, off);
    if (lane == 0) wsum[wid] = acc;
    __syncthreads();
    if (threadIdx.x == 0) {
        float t = 0.0f;
        for (int w = 0; w < 16; ++w) t += wsum[w];
        out[0] = t;
    }
}

extern "C" void kernel_launch(void* const* d_in, const int* in_sizes, int n_in,
                              void* d_out, int out_size, void* d_ws, size_t ws_size,
                              hipStream_t stream) {
    const float* outp  = (const float*)d_in[0];   // [B,16] logits
    const float* score = (const float*)d_in[1];   // [B]
    float* out = (float*)d_out;

    int B  = in_sizes[1];
    int nb = (B + TPB - 1) / TPB;

    float* bpart = (float*)d_ws;

    k_fused<<<nb, TPB, 0, stream>>>(outp, score, bpart, B);
    k2_sum<<<1, 1024, 0, stream>>>(bpart, nb, out);
}

// Round 11
// 36.277 us; speedup vs baseline: 1.1569x; 1.1569x over previous
//
#include <hip/hip_runtime.h>

#define TPB 512
#define NW  (TPB / 64)   // 8 waves per block

__device__ __forceinline__ float pair_loss(float p0, float s0, float p1, float s1) {
    float dp = p0 - p1;
    float ds = s0 - s1;
    float sg = (ds > 0.0f) ? 1.0f : ((ds < 0.0f) ? -1.0f : 0.0f);
    float t  = dp * sg;
    // stable softplus(-t) = max(-t,0) + log1p(exp(-|t|))
    return fmaxf(-t, 0.0f) + log1pf(__expf(-fabsf(t)));
}

// direct-global per-row stats (rare boundary-scan path only)
__device__ __forceinline__ void row_stats(const float* __restrict__ outp, int row,
                                          float& p, bool& mask) {
    const float4* o4 = (const float4*)outp + (size_t)row * 4;
    float4 a = o4[0];
    float4 b = o4[1];
    float4 c = o4[2];
    float4 d = o4[3];
    float m01 = fmaxf(fmaxf(a.x, a.y), fmaxf(a.z, a.w));
    float m23 = fmaxf(fmaxf(b.x, b.y), fmaxf(b.z, b.w));
    float m45 = fmaxf(fmaxf(c.x, c.y), fmaxf(c.z, c.w));
    float m67 = fmaxf(fmaxf(d.x, d.y), fmaxf(d.z, d.w));
    float m = fmaxf(fmaxf(m01, m23), fmaxf(m45, m67));
    float sum = __expf(a.x - m) + __expf(a.y - m) + __expf(a.z - m) + __expf(a.w - m)
              + __expf(b.x - m) + __expf(b.y - m) + __expf(b.z - m) + __expf(b.w - m)
              + __expf(c.x - m) + __expf(c.y - m) + __expf(c.z - m) + __expf(c.w - m)
              + __expf(d.x - m) + __expf(d.y - m) + __expf(d.z - m) + __expf(d.w - m);
    p = __builtin_amdgcn_rcpf(sum);
    mask = (a.x == m);
}

// k1: contiguous 1KB-per-instruction global loads staged through per-wave LDS
//     (XOR-swizzled), then R6's exact pair phase + forward boundary scan.
__global__ void __launch_bounds__(TPB) k_fused(const float* __restrict__ outp,
                                               const float* __restrict__ score,
                                               float* __restrict__ bpart, int B) {
    __shared__ float4 stage[NW][64][4];   // 32 KB, wave-private regions
    __shared__ float sp[TPB];
    __shared__ float ss[TPB];
    __shared__ unsigned long long wmask[NW];
    __shared__ float wsum[NW];

    int tid  = threadIdx.x;
    int lane = tid & 63;
    int wid  = tid >> 6;
    int row  = blockIdx.x * TPB + tid;

    // ---- staging: 4 contiguous 1KB wave loads -> swizzled LDS ----
    {
        const float4* g4 = (const float4*)outp;
        size_t f0   = (size_t)(blockIdx.x * TPB + (wid << 6)) * 4;
        size_t fend = (size_t)B * 4;
        float4 z = make_float4(0.f, 0.f, 0.f, 0.f);
#pragma unroll
        for (int i = 0; i < 4; ++i) {
            size_t gi = f0 + i * 64 + lane;
            float4 v  = (gi < fend) ? g4[gi] : z;
            int idx = i * 64 + lane;          // 0..255 within wave span
            int r   = idx >> 2;               // row within wave (0..63)
            int j   = idx & 3;                // float4 block within row
            stage[wid][r][j ^ (r & 3)] = v;   // XOR swizzle (bank spread)
        }
    }
    // wave-local RAW through LDS: compiler inserts lgkmcnt, no barrier needed
    int l3 = lane & 3;
    float4 a = stage[wid][lane][0 ^ l3];
    float4 b = stage[wid][lane][1 ^ l3];
    float4 c = stage[wid][lane][2 ^ l3];
    float4 d = stage[wid][lane][3 ^ l3];

    bool mask = false;
    float p = 0.0f, s = 0.0f;
    {
        float m01 = fmaxf(fmaxf(a.x, a.y), fmaxf(a.z, a.w));
        float m23 = fmaxf(fmaxf(b.x, b.y), fmaxf(b.z, b.w));
        float m45 = fmaxf(fmaxf(c.x, c.y), fmaxf(c.z, c.w));
        float m67 = fmaxf(fmaxf(d.x, d.y), fmaxf(d.z, d.w));
        float m = fmaxf(fmaxf(m01, m23), fmaxf(m45, m67));
        float sum = __expf(a.x - m) + __expf(a.y - m) + __expf(a.z - m) + __expf(a.w - m)
                  + __expf(b.x - m) + __expf(b.y - m) + __expf(b.z - m) + __expf(b.w - m)
                  + __expf(c.x - m) + __expf(c.y - m) + __expf(c.z - m) + __expf(c.w - m)
                  + __expf(d.x - m) + __expf(d.y - m) + __expf(d.z - m) + __expf(d.w - m);
        p = __builtin_amdgcn_rcpf(sum);
        mask = (a.x == m) && (row < B);
        s = (row < B) ? score[row] : 0.0f;   // coalesced
    }
    sp[tid] = p;
    ss[tid] = s;

    unsigned long long bal = __ballot(mask);
    if (lane == 0) wmask[wid] = bal;
    __syncthreads();

    float acc = 0.0f;
    if (mask) {
        // next selected thread index within this block
        unsigned long long above = bal & ~((2ull << lane) - 1ull); // lane63 -> 0
        int nxt = -1;
        if (above) {
            nxt = (wid << 6) + __ffsll(above) - 1;
        } else {
            for (int w = wid + 1; w < NW; ++w)
                if (wmask[w]) { nxt = (w << 6) + __ffsll(wmask[w]) - 1; break; }
        }
        if (nxt >= 0) acc = pair_loss(p, s, sp[nxt], ss[nxt]);
    }

    // wave 0: cross-block pair via forward scan into following rows
    if (wid == 0) {
        int last = -1;
        for (int w = NW - 1; w >= 0; --w)
            if (wmask[w]) { last = (w << 6) + 63 - __clzll(wmask[w]); break; }
        if (last >= 0) {
            float pl = sp[last];
            float sl = ss[last];
            int base = blockIdx.x * TPB + TPB;
            while (base < B) {
                int r = base + lane;
                bool sel = false;
                float pf = 0.0f, sf = 0.0f;
                if (r < B) {
                    row_stats(outp, r, pf, sel);
                    sf = score[r];
                }
                unsigned long long b2 = __ballot(sel);
                if (b2) {
                    int fl = __ffsll(b2) - 1;
                    float pfirst = __shfl(pf, fl);
                    float sfirst = __shfl(sf, fl);
                    if (lane == 0) acc += pair_loss(pl, sl, pfirst, sfirst);
                    break;
                }
                base += 64;
            }
        }
    }

    // block reduce -> contention-free partial write
    for (int off = 32; off > 0; off >>= 1) acc += __shfl_down(acc, off);
    if (lane == 0) wsum[wid] = acc;
    __syncthreads();
    if (tid == 0) {
        float t = 0.0f;
        for (int w = 0; w < NW; ++w) t += wsum[w];
        bpart[blockIdx.x] = t;
    }
}

// k2: single block sums the per-block partials, writes out[0].
__global__ void k2_sum(const float* __restrict__ bpart, int nb,
                       float* __restrict__ out) {
    __shared__ float wsum[16];
    float acc = 0.0f;
    for (int b = threadIdx.x; b < nb; b += 1024) acc += bpart[b];
    int lane = threadIdx.x & 63;
    int wid  = threadIdx.x >> 6;
    for (int off = 32; off > 0; off >>= 1) acc += __shfl_down(acc, off);
    if (lane == 0) wsum[wid] = acc;
    __syncthreads();
    if (threadIdx.x == 0) {
        float t = 0.0f;
        for (int w = 0; w < 16; ++w) t += wsum[w];
        out[0] = t;
    }
}

extern "C" void kernel_launch(void* const* d_in, const int* in_sizes, int n_in,
                              void* d_out, int out_size, void* d_ws, size_t ws_size,
                              hipStream_t stream) {
    const float* outp  = (const float*)d_in[0];   // [B,16] logits
    const float* score = (const float*)d_in[1];   // [B]
    float* out = (float*)d_out;

    int B  = in_sizes[1];
    int nb = (B + TPB - 1) / TPB;

    float* bpart = (float*)d_ws;

    k_fused<<<nb, TPB, 0, stream>>>(outp, score, bpart, B);
    k2_sum<<<1, 1024, 0, stream>>>(bpart, nb, out);
}

// Round 12
// 32.821 us; speedup vs baseline: 1.2788x; 1.1053x over previous
//
#include <hip/hip_runtime.h>

#define TPB 512
#define NW  (TPB / 64)   // 8 waves per block

__device__ __forceinline__ float pair_loss(float p0, float s0, float p1, float s1) {
    float dp = p0 - p1;
    float ds = s0 - s1;
    float sg = (ds > 0.0f) ? 1.0f : ((ds < 0.0f) ? -1.0f : 0.0f);
    float t  = dp * sg;
    // stable softplus(-t) = max(-t,0) + log1p(exp(-|t|))
    return fmaxf(-t, 0.0f) + log1pf(__expf(-fabsf(t)));
}

// Row's top softmax prob p and mask (argmax==0) from 16 logits.
__device__ __forceinline__ void row_stats(const float* __restrict__ outp, int row,
                                          float& p, bool& mask) {
    const float4* o4 = (const float4*)outp + (size_t)row * 4;
    float4 a = o4[0];
    float4 b = o4[1];
    float4 c = o4[2];
    float4 d = o4[3];
    float m01 = fmaxf(fmaxf(a.x, a.y), fmaxf(a.z, a.w));
    float m23 = fmaxf(fmaxf(b.x, b.y), fmaxf(b.z, b.w));
    float m45 = fmaxf(fmaxf(c.x, c.y), fmaxf(c.z, c.w));
    float m67 = fmaxf(fmaxf(d.x, d.y), fmaxf(d.z, d.w));
    float m = fmaxf(fmaxf(m01, m23), fmaxf(m45, m67));
    float sum = __expf(a.x - m) + __expf(a.y - m) + __expf(a.z - m) + __expf(a.w - m)
              + __expf(b.x - m) + __expf(b.y - m) + __expf(b.z - m) + __expf(b.w - m)
              + __expf(c.x - m) + __expf(c.y - m) + __expf(c.z - m) + __expf(c.w - m)
              + __expf(d.x - m) + __expf(d.y - m) + __expf(d.z - m) + __expf(d.w - m);
    p = __builtin_amdgcn_rcpf(sum);   // ~1ulp approx; tolerance is huge
    mask = (a.x == m);
}

// k1: R6 body, but the boundary scan is moved AFTER the block reduction so
//     waves 1-7 retire early and nobody waits on wave 0's serial scan.
__global__ void __launch_bounds__(TPB) k_fused(const float* __restrict__ outp,
                                               const float* __restrict__ score,
                                               float* __restrict__ bpart,
                                               float* __restrict__ bbound, int B) {
    __shared__ float sp[TPB];
    __shared__ float ss[TPB];
    __shared__ unsigned long long wmask[NW];
    __shared__ float wsum[NW];

    int tid  = threadIdx.x;
    int lane = tid & 63;
    int wid  = tid >> 6;
    int row  = blockIdx.x * TPB + tid;

    bool mask = false;
    float p = 0.0f, s = 0.0f;
    if (row < B) {
        row_stats(outp, row, p, mask);
        s = score[row];                // coalesced
    }
    sp[tid] = p;
    ss[tid] = s;

    unsigned long long bal = __ballot(mask);
    if (lane == 0) wmask[wid] = bal;
    __syncthreads();

    float acc = 0.0f;
    if (mask) {
        // next selected thread index within this block
        unsigned long long above = bal & ~((2ull << lane) - 1ull); // lane 63: (2<<63)==0 -> 0
        int nxt = -1;
        if (above) {
            nxt = (wid << 6) + __ffsll(above) - 1;
        } else {
            for (int w = wid + 1; w < NW; ++w)
                if (wmask[w]) { nxt = (w << 6) + __ffsll(wmask[w]) - 1; break; }
        }
        if (nxt >= 0) acc = pair_loss(p, s, sp[nxt], ss[nxt]);
    }

    // block reduce of the MAIN loss -> bpart; waves 1-7 exit right after.
    for (int off = 32; off > 0; off >>= 1) acc += __shfl_down(acc, off);
    if (lane == 0) wsum[wid] = acc;
    __syncthreads();
    if (wid != 0) return;              // early retirement for waves 1-7

    if (tid == 0) {
        float t = 0.0f;
        for (int w = 0; w < NW; ++w) t += wsum[w];
        bpart[blockIdx.x] = t;
    }

    // wave 0 alone (no barriers ahead): cross-block boundary pair via forward
    // scan. sp/ss/wmask are still valid; no other wave reads/writes them.
    float bl = 0.0f;
    int last = -1;
    for (int w = NW - 1; w >= 0; --w)
        if (wmask[w]) { last = (w << 6) + 63 - __clzll(wmask[w]); break; }
    if (last >= 0) {
        float pl = sp[last];
        float sl = ss[last];
        int base = blockIdx.x * TPB + TPB;
        while (base < B) {
            int r = base + lane;
            bool sel = false;
            float pf = 0.0f, sf = 0.0f;
            if (r < B) {
                row_stats(outp, r, pf, sel);
                sf = score[r];
            }
            unsigned long long b2 = __ballot(sel);
            if (b2) {
                int fl = __ffsll(b2) - 1;
                float pfirst = __shfl(pf, fl);
                float sfirst = __shfl(sf, fl);
                bl = pair_loss(pl, sl, pfirst, sfirst);
                break;
            }
            base += 64;
        }
    }
    if (lane == 0) bbound[blockIdx.x] = bl;   // unconditional write (ws not zeroed)
}

// k2: single block sums bpart[0..nb) ++ bbound[0..nb) (contiguous 2*nb floats).
__global__ void k2_sum(const float* __restrict__ parts, int n2,
                       float* __restrict__ out) {
    __shared__ float wsum[16];
    float acc = 0.0f;
    for (int b = threadIdx.x; b < n2; b += 1024) acc += parts[b];
    int lane = threadIdx.x & 63;
    int wid  = threadIdx.x >> 6;
    for (int off = 32; off > 0; off >>= 1) acc += __shfl_down(acc, off);
    if (lane == 0) wsum[wid] = acc;
    __syncthreads();
    if (threadIdx.x == 0) {
        float t = 0.0f;
        for (int w = 0; w < 16; ++w) t += wsum[w];
        out[0] = t;
    }
}

extern "C" void kernel_launch(void* const* d_in, const int* in_sizes, int n_in,
                              void* d_out, int out_size, void* d_ws, size_t ws_size,
                              hipStream_t stream) {
    const float* outp  = (const float*)d_in[0];   // [B,16] logits
    const float* score = (const float*)d_in[1];   // [B]
    float* out = (float*)d_out;

    int B  = in_sizes[1];
    int nb = (B + TPB - 1) / TPB;

    float* bpart  = (float*)d_ws;        // [nb]
    float* bbound = bpart + nb;          // [nb], contiguous with bpart

    k_fused<<<nb, TPB, 0, stream>>>(outp, score, bpart, bbound, B);
    k2_sum<<<1, 1024, 0, stream>>>(bpart, 2 * nb, out);
}

// Round 13
// 31.679 us; speedup vs baseline: 1.3249x; 1.0360x over previous
//
#include <hip/hip_runtime.h>

#define TPB 512
#define NW  (TPB / 64)   // 8 waves per block

__device__ __forceinline__ float pair_loss(float p0, float s0, float p1, float s1) {
    float dp = p0 - p1;
    float ds = s0 - s1;
    float sg = (ds > 0.0f) ? 1.0f : ((ds < 0.0f) ? -1.0f : 0.0f);
    float t  = dp * sg;
    // stable softplus(-t) = max(-t,0) + log1p(exp(-|t|))
    return fmaxf(-t, 0.0f) + log1pf(__expf(-fabsf(t)));
}

// Row's top softmax prob p and mask (argmax==0) from 16 logits.
__device__ __forceinline__ void row_stats(const float* __restrict__ outp, int row,
                                          float& p, bool& mask) {
    const float4* o4 = (const float4*)outp + (size_t)row * 4;
    float4 a = o4[0];
    float4 b = o4[1];
    float4 c = o4[2];
    float4 d = o4[3];
    float m01 = fmaxf(fmaxf(a.x, a.y), fmaxf(a.z, a.w));
    float m23 = fmaxf(fmaxf(b.x, b.y), fmaxf(b.z, b.w));
    float m45 = fmaxf(fmaxf(c.x, c.y), fmaxf(c.z, c.w));
    float m67 = fmaxf(fmaxf(d.x, d.y), fmaxf(d.z, d.w));
    float m = fmaxf(fmaxf(m01, m23), fmaxf(m45, m67));
    float sum = __expf(a.x - m) + __expf(a.y - m) + __expf(a.z - m) + __expf(a.w - m)
              + __expf(b.x - m) + __expf(b.y - m) + __expf(b.z - m) + __expf(b.w - m)
              + __expf(c.x - m) + __expf(c.y - m) + __expf(c.z - m) + __expf(c.w - m)
              + __expf(d.x - m) + __expf(d.y - m) + __expf(d.z - m) + __expf(d.w - m);
    p = __builtin_amdgcn_rcpf(sum);   // ~1ulp approx; tolerance is huge
    mask = (a.x == m);
}

// k1: 1 row/thread, 512-thread blocks. Block-local adjacent-selected pairs +
//     own cross-boundary pair via forward scan; per-block partial (no atomics).
__global__ void __launch_bounds__(TPB) k_fused(const float* __restrict__ outp,
                                               const float* __restrict__ score,
                                               float* __restrict__ bpart, int B) {
    __shared__ float sp[TPB];
    __shared__ float ss[TPB];
    __shared__ unsigned long long wmask[NW];
    __shared__ float wsum[NW];

    int tid  = threadIdx.x;
    int lane = tid & 63;
    int wid  = tid >> 6;
    int row  = blockIdx.x * TPB + tid;

    bool mask = false;
    float p = 0.0f, s = 0.0f;
    if (row < B) {
        row_stats(outp, row, p, mask);
        s = score[row];                // coalesced
    }
    sp[tid] = p;
    ss[tid] = s;

    unsigned long long bal = __ballot(mask);
    if (lane == 0) wmask[wid] = bal;
    __syncthreads();

    float acc = 0.0f;
    if (mask) {
        // next selected thread index within this block
        unsigned long long above = bal & ~((2ull << lane) - 1ull); // lane 63: (2<<63)==0 -> above=0
        int nxt = -1;
        if (above) {
            nxt = (wid << 6) + __ffsll(above) - 1;
        } else {
            for (int w = wid + 1; w < NW; ++w)
                if (wmask[w]) { nxt = (w << 6) + __ffsll(wmask[w]) - 1; break; }
        }
        if (nxt >= 0) acc = pair_loss(p, s, sp[nxt], ss[nxt]);
    }

    // wave 0: cross-boundary pair via forward scan into following rows
    // (runs concurrently with other waves' pair loop above)
    if (wid == 0) {
        int last = -1;
        for (int w = NW - 1; w >= 0; --w)
            if (wmask[w]) { last = (w << 6) + 63 - __clzll(wmask[w]); break; }
        if (last >= 0) {
            float pl = sp[last];
            float sl = ss[last];
            int base = (blockIdx.x + 1) * TPB;
            while (base < B) {
                int r = base + lane;
                bool sel = false;
                float pf = 0.0f, sf = 0.0f;
                if (r < B) {
                    row_stats(outp, r, pf, sel);
                    sf = score[r];
                }
                unsigned long long b2 = __ballot(sel);
                if (b2) {
                    int fl = __ffsll(b2) - 1;
                    float pfirst = __shfl(pf, fl);
                    float sfirst = __shfl(sf, fl);
                    if (lane == 0) acc += pair_loss(pl, sl, pfirst, sfirst);
                    break;
                }
                base += 64;
            }
        }
    }

    // block reduce -> contention-free partial write
    for (int off = 32; off > 0; off >>= 1) acc += __shfl_down(acc, off);
    if (lane == 0) wsum[wid] = acc;
    __syncthreads();
    if (tid == 0) {
        float t = 0.0f;
        for (int w = 0; w < NW; ++w) t += wsum[w];
        bpart[blockIdx.x] = t;
    }
}

// k2: single block sums the per-block partials, writes out[0].
__global__ void k2_sum(const float* __restrict__ bpart, int nb,
                       float* __restrict__ out) {
    __shared__ float wsum[16];
    float acc = 0.0f;
    for (int b = threadIdx.x; b < nb; b += 1024) acc += bpart[b];
    int lane = threadIdx.x & 63;
    int wid  = threadIdx.x >> 6;
    for (int off = 32; off > 0; off >>= 1) acc += __shfl_down(acc, off);
    if (lane == 0) wsum[wid] = acc;
    __syncthreads();
    if (threadIdx.x == 0) {
        float t = 0.0f;
        for (int w = 0; w < 16; ++w) t += wsum[w];
        out[0] = t;
    }
}

extern "C" void kernel_launch(void* const* d_in, const int* in_sizes, int n_in,
                              void* d_out, int out_size, void* d_ws, size_t ws_size,
                              hipStream_t stream) {
    const float* outp  = (const float*)d_in[0];   // [B,16] logits
    const float* score = (const float*)d_in[1];   // [B]
    float* out = (float*)d_out;

    int B  = in_sizes[1];
    int nb = (B + TPB - 1) / TPB;

    float* bpart = (float*)d_ws;

    k_fused<<<nb, TPB, 0, stream>>>(outp, score, bpart, B);
    k2_sum<<<1, 1024, 0, stream>>>(bpart, nb, out);
}